// Round 9
// baseline (411.290 us; speedup 1.0000x reference)
//
#include <hip/hip_runtime.h>

#define NN 50000
#define NE 800000
#define FIN 256
#define HD 128
#define CAP 96   // max bucketed in-degree; Poisson(16) over 50K nodes maxes ~45

typedef unsigned int uint;
typedef unsigned short ushort;
typedef __attribute__((ext_vector_type(8))) short short8v;   // 8 bf16 (4 VGPRs)
typedef __attribute__((ext_vector_type(4))) float f32x4;

__device__ inline ushort f2bf(float f) {          // round-to-nearest-even bf16
    uint u = __float_as_uint(f);
    u += 0x7fffu + ((u >> 16) & 1u);
    return (ushort)(u >> 16);
}
__device__ inline float bf2f(ushort h) { return __uint_as_float(((uint)h) << 16); }
__device__ inline void unpack2(uint u, float& a, float& b) {
    a = __uint_as_float(u << 16);
    b = __uint_as_float(u & 0xffff0000u);
}

// ---------------- graph build ----------------

__global__ void build_buckets(const int* __restrict__ ei, int* __restrict__ cnt,
                              int* __restrict__ bucket) {
    int e = blockIdx.x * 256 + threadIdx.x;
    if (e >= NE) return;
    int s = ei[e];
    int d = ei[NE + e];
    int pos = atomicAdd(&cnt[d], 1);
    if (pos < CAP) bucket[d * CAP + pos] = s;
}

__global__ void compute_dinv(const int* __restrict__ cnt, float* __restrict__ dinv) {
    int v = blockIdx.x * 256 + threadIdx.x;
    if (v < NN) dinv[v] = rsqrtf((float)cnt[v] + 1.0f);  // +1 self-loop
}

// ---------------- W prep: Wt[col][k] = bf16(W[k][col]) ----------------

template<int K>
__global__ void prep_wt(const float* __restrict__ W, ushort* __restrict__ Wt) {
    int idx = blockIdx.x * 256 + threadIdx.x;
    if (idx >= K * 128) return;
    int k = idx >> 7, col = idx & 127;
    Wt[col * K + k] = f2bf(W[idx]);
}

// ---------------- MFMA GEMM: Cbf16[r,:] = dscale[r] * (A[M,K] @ W[K,128])[r,:] ----------------
// A fp32 (hi/lo bf16 split in staging: error ~2^-18), Wt pre-cast bf16 [128][K].
// BM=64 (4 waves x 16 rows), BN=128, BK=32. 16x16x32 bf16 MFMA.

template<int K>
__global__ __launch_bounds__(256) void gemm_mfma(const float* __restrict__ A,
                                                 const ushort* __restrict__ Wt,
                                                 const float* __restrict__ dscale,
                                                 ushort* __restrict__ C, int M) {
    __shared__ ushort Ah[64][40];    // pad 32->40: uniform bank spread for b128 frag reads
    __shared__ ushort Al[64][40];
    __shared__ ushort Bt[128][40];
    const int tid  = threadIdx.x;
    const int wid  = tid >> 6;        // wave id: rows wid*16..wid*16+15
    const int lane = tid & 63;
    const int fr   = lane & 15;       // frag row (A) / frag col (B)
    const int kg   = lane >> 4;       // k-group 0..3

    const int blockRow = blockIdx.x * 64;

    f32x4 acc[8];
#pragma unroll
    for (int n = 0; n < 8; ++n) acc[n] = (f32x4){0.f, 0.f, 0.f, 0.f};

    const int s_ar = tid >> 3;            // A-staging row within half (0..31)
    const int s_ak = (tid & 7) << 2;      // A-staging k offset (0..28)

    for (int k0 = 0; k0 < K; k0 += 32) {
#pragma unroll
        for (int i = 0; i < 2; ++i) {
            int r = i * 32 + s_ar;
            int row = blockRow + r;
            float4 av = make_float4(0.f, 0.f, 0.f, 0.f);
            if (row < M) av = *(const float4*)(A + (size_t)row * K + k0 + s_ak);
            ushort h0 = f2bf(av.x), h1 = f2bf(av.y), h2 = f2bf(av.z), h3 = f2bf(av.w);
            ushort l0 = f2bf(av.x - bf2f(h0)), l1 = f2bf(av.y - bf2f(h1));
            ushort l2 = f2bf(av.z - bf2f(h2)), l3 = f2bf(av.w - bf2f(h3));
            uint2 hw, lw;
            hw.x = (uint)h0 | ((uint)h1 << 16); hw.y = (uint)h2 | ((uint)h3 << 16);
            lw.x = (uint)l0 | ((uint)l1 << 16); lw.y = (uint)l2 | ((uint)l3 << 16);
            *(uint2*)&Ah[r][s_ak] = hw;
            *(uint2*)&Al[r][s_ak] = lw;
        }
#pragma unroll
        for (int i = 0; i < 2; ++i) {
            int id = i * 256 + tid;
            int col = id >> 2;
            int kc = (id & 3) << 3;
            *(uint4*)&Bt[col][kc] = *(const uint4*)(Wt + (size_t)col * K + k0 + kc);
        }
        __syncthreads();
        short8v a_h = *(short8v*)&Ah[(wid << 4) + fr][kg << 3];
        short8v a_l = *(short8v*)&Al[(wid << 4) + fr][kg << 3];
#pragma unroll
        for (int n = 0; n < 8; ++n) {
            short8v b = *(short8v*)&Bt[(n << 4) + fr][kg << 3];
            acc[n] = __builtin_amdgcn_mfma_f32_16x16x32_bf16(a_h, b, acc[n], 0, 0, 0);
            acc[n] = __builtin_amdgcn_mfma_f32_16x16x32_bf16(a_l, b, acc[n], 0, 0, 0);
        }
        __syncthreads();
    }

    const int rbase = blockRow + (wid << 4) + (kg << 2);
#pragma unroll
    for (int r = 0; r < 4; ++r) {
        int row = rbase + r;
        if (row < M) {
            float ds = dscale[row];
#pragma unroll
            for (int n = 0; n < 8; ++n)
                C[(size_t)row * 128 + (n << 4) + fr] = f2bf(ds * acc[n][r]);
        }
    }
}

// ---------------- aggregation: 4 nodes per wave, continuous padded slot stream ----------------
// hb rows are dinv[r]*h[r] (bf16); row NN is all-zero (mask/pad target).
// Each node occupies ceil((c+1)/4) chunks of 4 slots (slot c = self-loop, rest padded to zero row).
// Lane l: group g=l>>4 owns slot 4t+g of chunk t; octet q=l&15 owns features q*8..q*8+7.
// Flush (combine+store+optional heads) at wave-uniform node boundaries; prologue amortized 4x.

template<int RELU, int HEADS>
__global__ __launch_bounds__(256) void aggregate(const ushort* __restrict__ hb,
                                                 const int* __restrict__ cnt,
                                                 const int* __restrict__ bucket,
                                                 const float* __restrict__ dinv,
                                                 const float* __restrict__ bias,
                                                 float* __restrict__ out,
                                                 const float* __restrict__ Wh1,
                                                 const float* __restrict__ bh1,
                                                 const float* __restrict__ Wh2,
                                                 const float* __restrict__ bh2,
                                                 float* __restrict__ out1,
                                                 float* __restrict__ out2) {
    const int wv = blockIdx.x * 4 + (threadIdx.x >> 6);
    const int v0 = wv << 2;                  // 4 consecutive nodes; NN%4==0
    if (v0 >= NN) return;
    const int lane = threadIdx.x & 63;
    const int g = lane >> 4;
    const int q = lane & 15;

    const int c0 = min(cnt[v0], CAP),     c1 = min(cnt[v0 + 1], CAP),
              c2 = min(cnt[v0 + 2], CAP), c3 = min(cnt[v0 + 3], CAP);
    const float di0 = dinv[v0],     di1 = dinv[v0 + 1],
                di2 = dinv[v0 + 2], di3 = dinv[v0 + 3];
    const int tb1 = (c0 + 4) >> 2;           // chunk boundaries (>=1 per node)
    const int tb2 = tb1 + ((c1 + 4) >> 2);
    const int tb3 = tb2 + ((c2 + 4) >> 2);
    const int nch = tb3 + ((c3 + 4) >> 2);

    auto slot_index = [&](int t) -> int {
        if (t >= nch) return NN;
        int nd = (t >= tb1) + (t >= tb2) + (t >= tb3);
        int tb = nd == 0 ? 0  : nd == 1 ? tb1 : nd == 2 ? tb2 : tb3;
        int c  = nd == 0 ? c0 : nd == 1 ? c1  : nd == 2 ? c2  : c3;
        int idx = ((t - tb) << 2) + g;
        int vv = v0 + nd;
        return idx < c ? bucket[(size_t)vv * CAP + idx] : (idx == c ? vv : NN);
    };
    auto rowload = [&](int s) -> uint4 {
        return *(const uint4*)(hb + (size_t)s * 128 + (q << 3));
    };

    float acc[8];
#pragma unroll
    for (int j = 0; j < 8; ++j) acc[j] = 0.f;

    auto consume = [&](uint4 r) {
        float f0, f1, f2, f3, f4, f5, f6, f7;
        unpack2(r.x, f0, f1); unpack2(r.y, f2, f3);
        unpack2(r.z, f4, f5); unpack2(r.w, f6, f7);
        acc[0] += f0; acc[1] += f1; acc[2] += f2; acc[3] += f3;
        acc[4] += f4; acc[5] += f5; acc[6] += f6; acc[7] += f7;
    };

    auto flush = [&](int nd) {
        float o[8];
#pragma unroll
        for (int j = 0; j < 8; ++j) {
            float t = acc[j];
            t += __shfl_xor(t, 16);
            t += __shfl_xor(t, 32);
            o[j] = t;
            acc[j] = 0.f;
        }
        const float di = nd == 0 ? di0 : nd == 1 ? di1 : nd == 2 ? di2 : di3;
        const int v = v0 + nd;
        float4 bb0 = *(const float4*)(bias + (q << 3));
        float4 bb1 = *(const float4*)(bias + (q << 3) + 4);
        o[0] = fmaf(di, o[0], bb0.x); o[1] = fmaf(di, o[1], bb0.y);
        o[2] = fmaf(di, o[2], bb0.z); o[3] = fmaf(di, o[3], bb0.w);
        o[4] = fmaf(di, o[4], bb1.x); o[5] = fmaf(di, o[5], bb1.y);
        o[6] = fmaf(di, o[6], bb1.z); o[7] = fmaf(di, o[7], bb1.w);
        if (RELU) {
#pragma unroll
            for (int j = 0; j < 8; ++j) o[j] = fmaxf(o[j], 0.f);
        }
        if (g < 2) {
            int j0 = (g & 1) << 2;
            *(float4*)(out + (size_t)v * 128 + (q << 3) + j0) =
                make_float4(o[j0], o[j0 + 1], o[j0 + 2], o[j0 + 3]);
        }
        if (HEADS) {
            const int kb = q << 3;
            float p[7];
#pragma unroll
            for (int cc = 0; cc < 4; ++cc) {
                float s = 0.f;
#pragma unroll
                for (int j = 0; j < 8; ++j) s = fmaf(o[j], Wh1[(kb + j) * 4 + cc], s);
                p[cc] = s;
            }
#pragma unroll
            for (int cc = 0; cc < 3; ++cc) {
                float s = 0.f;
#pragma unroll
                for (int j = 0; j < 8; ++j) s = fmaf(o[j], Wh2[(kb + j) * 3 + cc], s);
                p[4 + cc] = s;
            }
#pragma unroll
            for (int i = 0; i < 7; ++i) {
                float s = p[i];
                s += __shfl_xor(s, 1);
                s += __shfl_xor(s, 2);
                s += __shfl_xor(s, 4);
                s += __shfl_xor(s, 8);
                p[i] = s;
            }
            if (lane == 0) {
                out1[(size_t)v * 4 + 0] = p[0] + bh1[0];
                out1[(size_t)v * 4 + 1] = p[1] + bh1[1];
                out1[(size_t)v * 4 + 2] = p[2] + bh1[2];
                out1[(size_t)v * 4 + 3] = p[3] + bh1[3];
                out2[(size_t)v * 3 + 0] = p[4] + bh2[0];
                out2[(size_t)v * 3 + 1] = p[5] + bh2[1];
                out2[(size_t)v * 3 + 2] = p[6] + bh2[2];
            }
        }
    };

    // pipeline: indices for chunks 0..3 issued together (independent), rows 2 chunks deep
    int sP2 = slot_index(2);
    int sP3 = slot_index(3);
    uint4 rA = rowload(slot_index(0));
    uint4 rB = rowload(slot_index(1));

    int nd = 0;
    int flushT = tb1 - 1;
    for (int t = 0; t < nch; ++t) {
        uint4 rN = rowload(sP2);
        sP2 = sP3;
        sP3 = slot_index(t + 4);
        consume(rA);
        if (t == flushT) {
            flush(nd);
            ++nd;
            flushT = nd == 1 ? tb2 - 1 : nd == 2 ? tb3 - 1 : nch - 1;
        }
        rA = rB; rB = rN;
    }
}

// ---------------- launch ----------------

extern "C" void kernel_launch(void* const* d_in, const int* in_sizes, int n_in,
                              void* d_out, int out_size, void* d_ws, size_t ws_size,
                              hipStream_t stream) {
    const float* x   = (const float*)d_in[0];
    const int*   ei  = (const int*)d_in[1];
    const float* W1  = (const float*)d_in[2];
    const float* b1  = (const float*)d_in[3];
    const float* W2  = (const float*)d_in[4];
    const float* b2  = (const float*)d_in[5];
    const float* Wh1 = (const float*)d_in[6];
    const float* bh1 = (const float*)d_in[7];
    const float* Wh2 = (const float*)d_in[8];
    const float* bh2 = (const float*)d_in[9];

    float* out1 = (float*)d_out;
    float* out2 = out1 + (size_t)NN * 4;
    float* hout = out2 + (size_t)NN * 3;   // output #3 written directly by aggregate<0,1>

    char* ws = (char*)d_ws;
    auto alloc = [&](size_t bytes) { char* p = ws; ws += (bytes + 255) & ~(size_t)255; return p; };
    int*    cnt    = (int*)   alloc((size_t)NN * 4);
    float*  dinv   = (float*) alloc((size_t)NN * 4);
    int*    bucket = (int*)   alloc((size_t)NN * CAP * 4);
    ushort* hlinb  = (ushort*)alloc((size_t)(NN + 1) * HD * 2);  // +1 zero row (mask target)
    float*  hagg   = (float*) alloc((size_t)NN * HD * 4);
    ushort* Wt1    = (ushort*)alloc((size_t)128 * FIN * 2);      // bf16 W1^T [col][K]
    ushort* Wt2    = (ushort*)alloc((size_t)128 * HD * 2);       // bf16 W2^T [col][K]

    hipMemsetAsync(cnt, 0, (size_t)NN * 4, stream);
    hipMemsetAsync(hlinb + (size_t)NN * HD, 0, HD * 2, stream);  // zero row NN
    build_buckets<<<(NE + 255) / 256, 256, 0, stream>>>(ei, cnt, bucket);
    compute_dinv<<<(NN + 255) / 256, 256, 0, stream>>>(cnt, dinv);
    prep_wt<FIN><<<(FIN * 128 + 255) / 256, 256, 0, stream>>>(W1, Wt1);
    prep_wt<HD><<<(HD * 128 + 255) / 256, 256, 0, stream>>>(W2, Wt2);

    // layer 1: hlinb = bf16(dinv .* (x @ W1)) ; hagg = relu(dinv*rowsum + b1)
    gemm_mfma<FIN><<<(NN + 63) / 64, 256, 0, stream>>>(x, Wt1, dinv, hlinb, NN);
    aggregate<1, 0><<<(NN + 15) / 16, 256, 0, stream>>>(hlinb, cnt, bucket, dinv, b1, hagg,
                                                        nullptr, nullptr, nullptr, nullptr,
                                                        nullptr, nullptr);

    // layer 2: hlinb = bf16(dinv .* (hagg @ W2)) ; hout = dinv*rowsum + b2 ; heads fused
    gemm_mfma<HD><<<(NN + 63) / 64, 256, 0, stream>>>(hagg, Wt2, dinv, hlinb, NN);
    aggregate<0, 1><<<(NN + 15) / 16, 256, 0, stream>>>(hlinb, cnt, bucket, dinv, b2, hout,
                                                        Wh1, bh1, Wh2, bh2, out1, out2);
}

// Round 11
// 301.731 us; speedup vs baseline: 1.3631x; 1.3631x over previous
//
#include <hip/hip_runtime.h>

#define NN 50000
#define NE 800000
#define FIN 256
#define HD 128
#define CAP 96   // max bucketed in-degree; Poisson(16) over 50K nodes maxes ~45

typedef unsigned int uint;
typedef unsigned short ushort;
typedef __attribute__((ext_vector_type(8))) short short8v;   // 8 bf16 (4 VGPRs)
typedef __attribute__((ext_vector_type(4))) float f32x4;

__device__ inline ushort f2bf(float f) {          // round-to-nearest-even bf16
    uint u = __float_as_uint(f);
    u += 0x7fffu + ((u >> 16) & 1u);
    return (ushort)(u >> 16);
}
__device__ inline void unpack2(uint u, float& a, float& b) {
    a = __uint_as_float(u << 16);
    b = __uint_as_float(u & 0xffff0000u);
}

// ---------------- graph build ----------------

__global__ void build_buckets(const int* __restrict__ ei, int* __restrict__ cnt,
                              int* __restrict__ bucket) {
    int e = blockIdx.x * 256 + threadIdx.x;
    if (e >= NE) return;
    int s = ei[e];
    int d = ei[NE + e];
    int pos = atomicAdd(&cnt[d], 1);
    if (pos < CAP) bucket[d * CAP + pos] = s;
}

__global__ void compute_dinv(const int* __restrict__ cnt, float* __restrict__ dinv) {
    int v = blockIdx.x * 256 + threadIdx.x;
    if (v < NN) dinv[v] = rsqrtf((float)cnt[v] + 1.0f);  // +1 self-loop
}

// ---------------- W prep: Wt[col][k] = bf16(W[k][col]) ----------------

template<int K>
__global__ void prep_wt(const float* __restrict__ W, ushort* __restrict__ Wt) {
    int idx = blockIdx.x * 256 + threadIdx.x;
    if (idx >= K * 128) return;
    int k = idx >> 7, col = idx & 127;
    Wt[col * K + k] = f2bf(W[idx]);
}

// ---------------- MFMA GEMM: Cbf16[r,:] = dscale[r] * (A[M,K] @ W[K,128])[r,:] ----------------
// A fp32 cast to bf16 in staging (single bf16: A-quant error ~ W-quant error, both invisible
// next to the bf16 h-row quantization per r6/r8 absmax evidence). Wt pre-cast bf16 [128][K].
// BM=64 (4 waves x 16 rows), BN=128, BK=32. 16x16x32 bf16 MFMA.

template<int K>
__global__ __launch_bounds__(256) void gemm_mfma(const float* __restrict__ A,
                                                 const ushort* __restrict__ Wt,
                                                 const float* __restrict__ dscale,
                                                 ushort* __restrict__ C, int M) {
    __shared__ ushort Ah[64][40];    // pad 32->40: uniform bank spread for b128 frag reads
    __shared__ ushort Bt[128][40];
    const int tid  = threadIdx.x;
    const int wid  = tid >> 6;        // wave id: rows wid*16..wid*16+15
    const int lane = tid & 63;
    const int fr   = lane & 15;       // frag row (A) / frag col (B)
    const int kg   = lane >> 4;       // k-group 0..3

    const int blockRow = blockIdx.x * 64;

    f32x4 acc[8];
#pragma unroll
    for (int n = 0; n < 8; ++n) acc[n] = (f32x4){0.f, 0.f, 0.f, 0.f};

    const int s_ar = tid >> 3;            // A-staging row within half (0..31)
    const int s_ak = (tid & 7) << 2;      // A-staging k offset (0..28)

    for (int k0 = 0; k0 < K; k0 += 32) {
#pragma unroll
        for (int i = 0; i < 2; ++i) {
            int r = i * 32 + s_ar;
            int row = blockRow + r;
            float4 av = make_float4(0.f, 0.f, 0.f, 0.f);
            if (row < M) av = *(const float4*)(A + (size_t)row * K + k0 + s_ak);
            uint2 hw;
            hw.x = (uint)f2bf(av.x) | ((uint)f2bf(av.y) << 16);
            hw.y = (uint)f2bf(av.z) | ((uint)f2bf(av.w) << 16);
            *(uint2*)&Ah[r][s_ak] = hw;
        }
#pragma unroll
        for (int i = 0; i < 2; ++i) {
            int id = i * 256 + tid;
            int col = id >> 2;
            int kc = (id & 3) << 3;
            *(uint4*)&Bt[col][kc] = *(const uint4*)(Wt + (size_t)col * K + k0 + kc);
        }
        __syncthreads();
        short8v a_h = *(short8v*)&Ah[(wid << 4) + fr][kg << 3];
#pragma unroll
        for (int n = 0; n < 8; ++n) {
            short8v b = *(short8v*)&Bt[(n << 4) + fr][kg << 3];
            acc[n] = __builtin_amdgcn_mfma_f32_16x16x32_bf16(a_h, b, acc[n], 0, 0, 0);
        }
        __syncthreads();
    }

    const int rbase = blockRow + (wid << 4) + (kg << 2);
#pragma unroll
    for (int r = 0; r < 4; ++r) {
        int row = rbase + r;
        if (row < M) {
            float ds = dscale[row];
#pragma unroll
            for (int n = 0; n < 8; ++n)
                C[(size_t)row * 128 + (n << 4) + fr] = f2bf(ds * acc[n][r]);
        }
    }
}

// ---------------- aggregation (round-6 version: pre-scaled bf16 rows; 3-stage pipeline) ----------------
// hb rows are dinv[r]*h[r]; row NN is all-zero (mask target).
// out[v] = dinv[v]*sum(rows) + b; optional relu; optional fused heads.
// Lane l: group g=l>>4 owns edge slots {8t+g, 8t+4+g}; octet q=l&15 owns features q*8..q*8+7.

template<int RELU, int HEADS>
__global__ __launch_bounds__(256) void aggregate(const ushort* __restrict__ hb,
                                                 const int* __restrict__ cnt,
                                                 const int* __restrict__ bucket,
                                                 const float* __restrict__ dinv,
                                                 const float* __restrict__ bias,
                                                 float* __restrict__ out,
                                                 const float* __restrict__ Wh1,
                                                 const float* __restrict__ bh1,
                                                 const float* __restrict__ Wh2,
                                                 const float* __restrict__ bh2,
                                                 float* __restrict__ out1,
                                                 float* __restrict__ out2) {
    int v = (blockIdx.x << 2) + (threadIdx.x >> 6);
    if (v >= NN) return;
    const int lane = threadIdx.x & 63;
    const int g = lane >> 4;
    const int q = lane & 15;
    int c = cnt[v]; if (c > CAP) c = CAP;
    const int total = c + 1;                 // +1 self-loop slot at index c
    const float di = dinv[v];
    const int* bk = bucket + (size_t)v * CAP;

    float acc[8];
#pragma unroll
    for (int j = 0; j < 8; ++j) acc[j] = 0.f;

    auto slotof = [&](int k) -> int {
        return k < c ? bk[k] : (k == c ? v : NN);
    };
    auto rowload = [&](int s) -> uint4 {
        return *(const uint4*)(hb + (size_t)s * 128 + (q << 3));
    };

    int sA = slotof(g);
    int sB = slotof(4 + g);
    uint4 rA = rowload(sA);
    uint4 rB = rowload(sB);
    int sC = slotof(8 + g);
    int sD = slotof(12 + g);

    for (int e = 0; e < total; e += 8) {
        uint4 rA2 = rowload(sC);
        uint4 rB2 = rowload(sD);
        sC = slotof(e + 16 + g);
        sD = slotof(e + 20 + g);
        float f0, f1, f2, f3, f4, f5, f6, f7;
        unpack2(rA.x, f0, f1); unpack2(rA.y, f2, f3);
        unpack2(rA.z, f4, f5); unpack2(rA.w, f6, f7);
        acc[0] += f0; acc[1] += f1; acc[2] += f2; acc[3] += f3;
        acc[4] += f4; acc[5] += f5; acc[6] += f6; acc[7] += f7;
        unpack2(rB.x, f0, f1); unpack2(rB.y, f2, f3);
        unpack2(rB.z, f4, f5); unpack2(rB.w, f6, f7);
        acc[0] += f0; acc[1] += f1; acc[2] += f2; acc[3] += f3;
        acc[4] += f4; acc[5] += f5; acc[6] += f6; acc[7] += f7;
        rA = rA2; rB = rB2;
    }

#pragma unroll
    for (int j = 0; j < 8; ++j) {
        acc[j] += __shfl_xor(acc[j], 16);
        acc[j] += __shfl_xor(acc[j], 32);
    }

    float4 bb0 = *(const float4*)(bias + (q << 3));
    float4 bb1 = *(const float4*)(bias + (q << 3) + 4);
    float o[8];
    o[0] = fmaf(di, acc[0], bb0.x); o[1] = fmaf(di, acc[1], bb0.y);
    o[2] = fmaf(di, acc[2], bb0.z); o[3] = fmaf(di, acc[3], bb0.w);
    o[4] = fmaf(di, acc[4], bb1.x); o[5] = fmaf(di, acc[5], bb1.y);
    o[6] = fmaf(di, acc[6], bb1.z); o[7] = fmaf(di, acc[7], bb1.w);
    if (RELU) {
#pragma unroll
        for (int j = 0; j < 8; ++j) o[j] = fmaxf(o[j], 0.f);
    }

    if (g < 2) {
        int j0 = (g & 1) << 2;
        *(float4*)(out + (size_t)v * 128 + (q << 3) + j0) =
            make_float4(o[j0], o[j0 + 1], o[j0 + 2], o[j0 + 3]);
    }

    if (HEADS) {
        const int kb = q << 3;
        float p[7];
#pragma unroll
        for (int cc = 0; cc < 4; ++cc) {
            float s = 0.f;
#pragma unroll
            for (int j = 0; j < 8; ++j) s = fmaf(o[j], Wh1[(kb + j) * 4 + cc], s);
            p[cc] = s;
        }
#pragma unroll
        for (int cc = 0; cc < 3; ++cc) {
            float s = 0.f;
#pragma unroll
            for (int j = 0; j < 8; ++j) s = fmaf(o[j], Wh2[(kb + j) * 3 + cc], s);
            p[4 + cc] = s;
        }
#pragma unroll
        for (int i = 0; i < 7; ++i) {
            float s = p[i];
            s += __shfl_xor(s, 1);
            s += __shfl_xor(s, 2);
            s += __shfl_xor(s, 4);
            s += __shfl_xor(s, 8);
            p[i] = s;
        }
        if (lane == 0) {
            out1[(size_t)v * 4 + 0] = p[0] + bh1[0];
            out1[(size_t)v * 4 + 1] = p[1] + bh1[1];
            out1[(size_t)v * 4 + 2] = p[2] + bh1[2];
            out1[(size_t)v * 4 + 3] = p[3] + bh1[3];
            out2[(size_t)v * 3 + 0] = p[4] + bh2[0];
            out2[(size_t)v * 3 + 1] = p[5] + bh2[1];
            out2[(size_t)v * 3 + 2] = p[6] + bh2[2];
        }
    }
}

// ---------------- launch ----------------

extern "C" void kernel_launch(void* const* d_in, const int* in_sizes, int n_in,
                              void* d_out, int out_size, void* d_ws, size_t ws_size,
                              hipStream_t stream) {
    const float* x   = (const float*)d_in[0];
    const int*   ei  = (const int*)d_in[1];
    const float* W1  = (const float*)d_in[2];
    const float* b1  = (const float*)d_in[3];
    const float* W2  = (const float*)d_in[4];
    const float* b2  = (const float*)d_in[5];
    const float* Wh1 = (const float*)d_in[6];
    const float* bh1 = (const float*)d_in[7];
    const float* Wh2 = (const float*)d_in[8];
    const float* bh2 = (const float*)d_in[9];

    float* out1 = (float*)d_out;
    float* out2 = out1 + (size_t)NN * 4;
    float* hout = out2 + (size_t)NN * 3;   // output #3 written directly by aggregate<0,1>

    char* ws = (char*)d_ws;
    auto alloc = [&](size_t bytes) { char* p = ws; ws += (bytes + 255) & ~(size_t)255; return p; };
    int*    cnt    = (int*)   alloc((size_t)NN * 4);
    float*  dinv   = (float*) alloc((size_t)NN * 4);
    int*    bucket = (int*)   alloc((size_t)NN * CAP * 4);
    ushort* hlinb  = (ushort*)alloc((size_t)(NN + 1) * HD * 2);  // +1 zero row (mask target)
    float*  hagg   = (float*) alloc((size_t)NN * HD * 4);
    ushort* Wt1    = (ushort*)alloc((size_t)128 * FIN * 2);      // bf16 W1^T [col][K]
    ushort* Wt2    = (ushort*)alloc((size_t)128 * HD * 2);       // bf16 W2^T [col][K]

    hipMemsetAsync(cnt, 0, (size_t)NN * 4, stream);
    hipMemsetAsync(hlinb + (size_t)NN * HD, 0, HD * 2, stream);  // zero row NN
    build_buckets<<<(NE + 255) / 256, 256, 0, stream>>>(ei, cnt, bucket);
    compute_dinv<<<(NN + 255) / 256, 256, 0, stream>>>(cnt, dinv);
    prep_wt<FIN><<<(FIN * 128 + 255) / 256, 256, 0, stream>>>(W1, Wt1);
    prep_wt<HD><<<(HD * 128 + 255) / 256, 256, 0, stream>>>(W2, Wt2);

    // layer 1: hlinb = bf16(dinv .* (x @ W1)) ; hagg = relu(dinv*rowsum + b1)
    gemm_mfma<FIN><<<(NN + 63) / 64, 256, 0, stream>>>(x, Wt1, dinv, hlinb, NN);
    aggregate<1, 0><<<(NN + 3) / 4, 256, 0, stream>>>(hlinb, cnt, bucket, dinv, b1, hagg,
                                                      nullptr, nullptr, nullptr, nullptr,
                                                      nullptr, nullptr);

    // layer 2: hlinb = bf16(dinv .* (hagg @ W2)) ; hout = dinv*rowsum + b2 ; heads fused
    gemm_mfma<HD><<<(NN + 63) / 64, 256, 0, stream>>>(hagg, Wt2, dinv, hlinb, NN);
    aggregate<0, 1><<<(NN + 3) / 4, 256, 0, stream>>>(hlinb, cnt, bucket, dinv, b2, hout,
                                                      Wh1, bh1, Wh2, bh2, out1, out2);
}

// Round 12
// 285.958 us; speedup vs baseline: 1.4383x; 1.0552x over previous
//
#include <hip/hip_runtime.h>

#define NN 50000
#define NE 800000
#define FIN 256
#define HD 128
#define CAP 96   // max bucketed in-degree; Poisson(16) over 50K nodes maxes ~45

typedef unsigned int uint;
typedef unsigned short ushort;
typedef __attribute__((ext_vector_type(8))) short short8v;   // 8 bf16 (4 VGPRs)
typedef __attribute__((ext_vector_type(4))) float f32x4;

__device__ inline ushort f2bf(float f) {          // round-to-nearest-even bf16
    uint u = __float_as_uint(f);
    u += 0x7fffu + ((u >> 16) & 1u);
    return (ushort)(u >> 16);
}
__device__ inline void unpack2(uint u, float& a, float& b) {
    a = __uint_as_float(u << 16);
    b = __uint_as_float(u & 0xffff0000u);
}

// ---------------- fused init: cnt=0, Wt1/Wt2 transpose+cast, hb zero row ----------------

__global__ void init_misc(const float* __restrict__ W1, ushort* __restrict__ Wt1,
                          const float* __restrict__ W2, ushort* __restrict__ Wt2,
                          int* __restrict__ cnt, ushort* __restrict__ zrow) {
    int id = blockIdx.x * 256 + threadIdx.x;
    if (id < NN) cnt[id] = 0;
    if (id < FIN * 128) { int k = id >> 7, c = id & 127; Wt1[c * FIN + k] = f2bf(W1[id]); }
    if (id < HD * 128)  { int k = id >> 7, c = id & 127; Wt2[c * HD + k]  = f2bf(W2[id]); }
    if (id < 128) zrow[id] = 0;
}

__global__ void build_buckets(const int* __restrict__ ei, int* __restrict__ cnt,
                              int* __restrict__ bucket) {
    int e = blockIdx.x * 256 + threadIdx.x;
    if (e >= NE) return;
    int s = ei[e];
    int d = ei[NE + e];
    int pos = atomicAdd(&cnt[d], 1);
    if (pos < CAP) bucket[d * CAP + pos] = s;
}

// ---------------- MFMA GEMM: Cbf16[r,:] = rsqrt(cnt[r]+1) * (A[M,K] @ W[K,128])[r,:] ----------------
// BM=32 (grid 1563 -> ~6.1 blocks/CU, fixes grid-limited occupancy of the BM=64 version).
// 4 waves: wave (wr,wc) computes rows wr*16..+15, cols wc*64..+63 (4 n-frags).
// A: fp32 (ABF=0, f2bf in staging) or bf16 (ABF=1, plain copy). Wt pre-cast bf16 [128][K].

template<int K, int ABF>
__global__ __launch_bounds__(256) void gemm_mfma(const void* __restrict__ Av,
                                                 const ushort* __restrict__ Wt,
                                                 const int* __restrict__ cnt,
                                                 ushort* __restrict__ C, int M) {
    __shared__ ushort Ah[32][40];    // pad 32->40: bank spread for b128 frag reads
    __shared__ ushort Bt[128][40];
    const int tid  = threadIdx.x;
    const int wid  = tid >> 6;
    const int lane = tid & 63;
    const int fr   = lane & 15;       // frag row (A) / frag col (B)
    const int kg   = lane >> 4;       // k-group 0..3
    const int wrow = (wid >> 1) << 4; // 0 or 16
    const int ncol = (wid & 1) << 6;  // 0 or 64

    const int blockRow = blockIdx.x * 32;

    f32x4 acc[4];
#pragma unroll
    for (int n = 0; n < 4; ++n) acc[n] = (f32x4){0.f, 0.f, 0.f, 0.f};

    const int s_r  = tid >> 3;            // staging row 0..31
    const int s_k  = (tid & 7) << 2;      // staging k offset 0..28
    const int s_row = blockRow + s_r;

    for (int k0 = 0; k0 < K; k0 += 32) {
        if (ABF) {
            const ushort* A = (const ushort*)Av;
            uint2 v = make_uint2(0u, 0u);
            if (s_row < M) v = *(const uint2*)(A + (size_t)s_row * K + k0 + s_k);
            *(uint2*)&Ah[s_r][s_k] = v;
        } else {
            const float* A = (const float*)Av;
            float4 v = make_float4(0.f, 0.f, 0.f, 0.f);
            if (s_row < M) v = *(const float4*)(A + (size_t)s_row * K + k0 + s_k);
            uint2 hw;
            hw.x = (uint)f2bf(v.x) | ((uint)f2bf(v.y) << 16);
            hw.y = (uint)f2bf(v.z) | ((uint)f2bf(v.w) << 16);
            *(uint2*)&Ah[s_r][s_k] = hw;
        }
#pragma unroll
        for (int i = 0; i < 2; ++i) {
            int id = i * 256 + tid;
            int col = id >> 2;
            int kc = (id & 3) << 3;
            *(uint4*)&Bt[col][kc] = *(const uint4*)(Wt + (size_t)col * K + k0 + kc);
        }
        __syncthreads();
        short8v a = *(short8v*)&Ah[wrow + fr][kg << 3];
#pragma unroll
        for (int n = 0; n < 4; ++n) {
            short8v b = *(short8v*)&Bt[ncol + (n << 4) + fr][kg << 3];
            acc[n] = __builtin_amdgcn_mfma_f32_16x16x32_bf16(a, b, acc[n], 0, 0, 0);
        }
        __syncthreads();
    }

    const int rbase = blockRow + wrow + (kg << 2);
#pragma unroll
    for (int r = 0; r < 4; ++r) {
        int row = rbase + r;
        if (row < M) {
            float ds = rsqrtf((float)cnt[row] + 1.0f);
#pragma unroll
            for (int n = 0; n < 4; ++n)
                C[(size_t)row * 128 + ncol + (n << 4) + fr] = f2bf(ds * acc[n][r]);
        }
    }
}

// ---------------- aggregation (r6 core; di from cnt; optional bf16 output) ----------------
// hb rows are dinv[r]*h[r]; row NN is all-zero (mask target).
// out[v] = dinv[v]*sum(rows) + b; optional relu; optional fused heads.
// Lane l: group g=l>>4 owns edge slots {8t+g, 8t+4+g}; octet q=l&15 owns features q*8..q*8+7.

template<int RELU, int HEADS, int OBF>
__global__ __launch_bounds__(256) void aggregate(const ushort* __restrict__ hb,
                                                 const int* __restrict__ cnt,
                                                 const int* __restrict__ bucket,
                                                 const float* __restrict__ bias,
                                                 float* __restrict__ outf,
                                                 ushort* __restrict__ outb,
                                                 const float* __restrict__ Wh1,
                                                 const float* __restrict__ bh1,
                                                 const float* __restrict__ Wh2,
                                                 const float* __restrict__ bh2,
                                                 float* __restrict__ out1,
                                                 float* __restrict__ out2) {
    int v = (blockIdx.x << 2) + (threadIdx.x >> 6);
    if (v >= NN) return;
    const int lane = threadIdx.x & 63;
    const int g = lane >> 4;
    const int q = lane & 15;
    const int craw = cnt[v];
    const int c = craw < CAP ? craw : CAP;
    const int total = c + 1;                 // +1 self-loop slot at index c
    const float di = rsqrtf((float)craw + 1.0f);
    const int* bk = bucket + (size_t)v * CAP;

    float acc[8];
#pragma unroll
    for (int j = 0; j < 8; ++j) acc[j] = 0.f;

    auto slotof = [&](int k) -> int {
        return k < c ? bk[k] : (k == c ? v : NN);
    };
    auto rowload = [&](int s) -> uint4 {
        return *(const uint4*)(hb + (size_t)s * 128 + (q << 3));
    };

    int sA = slotof(g);
    int sB = slotof(4 + g);
    uint4 rA = rowload(sA);
    uint4 rB = rowload(sB);
    int sC = slotof(8 + g);
    int sD = slotof(12 + g);

    for (int e = 0; e < total; e += 8) {
        uint4 rA2 = rowload(sC);
        uint4 rB2 = rowload(sD);
        sC = slotof(e + 16 + g);
        sD = slotof(e + 20 + g);
        float f0, f1, f2, f3, f4, f5, f6, f7;
        unpack2(rA.x, f0, f1); unpack2(rA.y, f2, f3);
        unpack2(rA.z, f4, f5); unpack2(rA.w, f6, f7);
        acc[0] += f0; acc[1] += f1; acc[2] += f2; acc[3] += f3;
        acc[4] += f4; acc[5] += f5; acc[6] += f6; acc[7] += f7;
        unpack2(rB.x, f0, f1); unpack2(rB.y, f2, f3);
        unpack2(rB.z, f4, f5); unpack2(rB.w, f6, f7);
        acc[0] += f0; acc[1] += f1; acc[2] += f2; acc[3] += f3;
        acc[4] += f4; acc[5] += f5; acc[6] += f6; acc[7] += f7;
        rA = rA2; rB = rB2;
    }

#pragma unroll
    for (int j = 0; j < 8; ++j) {
        acc[j] += __shfl_xor(acc[j], 16);
        acc[j] += __shfl_xor(acc[j], 32);
    }

    float4 bb0 = *(const float4*)(bias + (q << 3));
    float4 bb1 = *(const float4*)(bias + (q << 3) + 4);
    float o[8];
    o[0] = fmaf(di, acc[0], bb0.x); o[1] = fmaf(di, acc[1], bb0.y);
    o[2] = fmaf(di, acc[2], bb0.z); o[3] = fmaf(di, acc[3], bb0.w);
    o[4] = fmaf(di, acc[4], bb1.x); o[5] = fmaf(di, acc[5], bb1.y);
    o[6] = fmaf(di, acc[6], bb1.z); o[7] = fmaf(di, acc[7], bb1.w);
    if (RELU) {
#pragma unroll
        for (int j = 0; j < 8; ++j) o[j] = fmaxf(o[j], 0.f);
    }

    if (OBF) {
        if (g == 0) {                        // 16 lanes store the full bf16 row
            uint4 w;
            w.x = (uint)f2bf(o[0]) | ((uint)f2bf(o[1]) << 16);
            w.y = (uint)f2bf(o[2]) | ((uint)f2bf(o[3]) << 16);
            w.z = (uint)f2bf(o[4]) | ((uint)f2bf(o[5]) << 16);
            w.w = (uint)f2bf(o[6]) | ((uint)f2bf(o[7]) << 16);
            *(uint4*)(outb + (size_t)v * 128 + (q << 3)) = w;
        }
    } else {
        if (g < 2) {
            int j0 = (g & 1) << 2;
            *(float4*)(outf + (size_t)v * 128 + (q << 3) + j0) =
                make_float4(o[j0], o[j0 + 1], o[j0 + 2], o[j0 + 3]);
        }
    }

    if (HEADS) {
        const int kb = q << 3;
        float p[7];
#pragma unroll
        for (int cc = 0; cc < 4; ++cc) {
            float s = 0.f;
#pragma unroll
            for (int j = 0; j < 8; ++j) s = fmaf(o[j], Wh1[(kb + j) * 4 + cc], s);
            p[cc] = s;
        }
#pragma unroll
        for (int cc = 0; cc < 3; ++cc) {
            float s = 0.f;
#pragma unroll
            for (int j = 0; j < 8; ++j) s = fmaf(o[j], Wh2[(kb + j) * 3 + cc], s);
            p[4 + cc] = s;
        }
#pragma unroll
        for (int i = 0; i < 7; ++i) {
            float s = p[i];
            s += __shfl_xor(s, 1);
            s += __shfl_xor(s, 2);
            s += __shfl_xor(s, 4);
            s += __shfl_xor(s, 8);
            p[i] = s;
        }
        if (lane == 0) {
            out1[(size_t)v * 4 + 0] = p[0] + bh1[0];
            out1[(size_t)v * 4 + 1] = p[1] + bh1[1];
            out1[(size_t)v * 4 + 2] = p[2] + bh1[2];
            out1[(size_t)v * 4 + 3] = p[3] + bh1[3];
            out2[(size_t)v * 3 + 0] = p[4] + bh2[0];
            out2[(size_t)v * 3 + 1] = p[5] + bh2[1];
            out2[(size_t)v * 3 + 2] = p[6] + bh2[2];
        }
    }
}

// ---------------- launch ----------------

extern "C" void kernel_launch(void* const* d_in, const int* in_sizes, int n_in,
                              void* d_out, int out_size, void* d_ws, size_t ws_size,
                              hipStream_t stream) {
    const float* x   = (const float*)d_in[0];
    const int*   ei  = (const int*)d_in[1];
    const float* W1  = (const float*)d_in[2];
    const float* b1  = (const float*)d_in[3];
    const float* W2  = (const float*)d_in[4];
    const float* b2  = (const float*)d_in[5];
    const float* Wh1 = (const float*)d_in[6];
    const float* bh1 = (const float*)d_in[7];
    const float* Wh2 = (const float*)d_in[8];
    const float* bh2 = (const float*)d_in[9];

    float* out1 = (float*)d_out;
    float* out2 = out1 + (size_t)NN * 4;
    float* hout = out2 + (size_t)NN * 3;   // output #3 written directly by aggregate<0,1,0>

    char* ws = (char*)d_ws;
    auto alloc = [&](size_t bytes) { char* p = ws; ws += (bytes + 255) & ~(size_t)255; return p; };
    int*    cnt    = (int*)   alloc((size_t)NN * 4);
    int*    bucket = (int*)   alloc((size_t)NN * CAP * 4);
    ushort* hlinb  = (ushort*)alloc((size_t)(NN + 1) * HD * 2);  // +1 zero row (mask target)
    ushort* haggb  = (ushort*)alloc((size_t)NN * HD * 2);        // bf16 relu(agg1) -> GEMM2 A
    ushort* Wt1    = (ushort*)alloc((size_t)128 * FIN * 2);      // bf16 W1^T [col][K]
    ushort* Wt2    = (ushort*)alloc((size_t)128 * HD * 2);       // bf16 W2^T [col][K]

    init_misc<<<(NN + 255) / 256, 256, 0, stream>>>(W1, Wt1, W2, Wt2, cnt,
                                                    hlinb + (size_t)NN * HD);
    build_buckets<<<(NE + 255) / 256, 256, 0, stream>>>(ei, cnt, bucket);

    // layer 1: hlinb = bf16(dinv .* (x @ W1)) ; haggb = bf16(relu(dinv*rowsum + b1))
    gemm_mfma<FIN, 0><<<(NN + 31) / 32, 256, 0, stream>>>(x, Wt1, cnt, hlinb, NN);
    aggregate<1, 0, 1><<<(NN + 3) / 4, 256, 0, stream>>>(hlinb, cnt, bucket, b1,
                                                         nullptr, haggb,
                                                         nullptr, nullptr, nullptr, nullptr,
                                                         nullptr, nullptr);

    // layer 2: hlinb = bf16(dinv .* (haggb @ W2)) ; hout = dinv*rowsum + b2 ; heads fused
    gemm_mfma<HD, 1><<<(NN + 31) / 32, 256, 0, stream>>>(haggb, Wt2, cnt, hlinb, NN);
    aggregate<0, 1, 0><<<(NN + 3) / 4, 256, 0, stream>>>(hlinb, cnt, bucket, b2,
                                                         hout, nullptr,
                                                         Wh1, bh1, Wh2, bh2, out1, out2);
}